// Round 1
// baseline (2876.430 us; speedup 1.0000x reference)
//
#include <hip/hip_runtime.h>
#include <math.h>

#define N 16384
#define IN_DIM 5000
#define HID 64
#define NLEV 11
#define SPLITK 32
#define KCH (N / SPLITK)   /* 512 */

// ---------------- level compaction ----------------
__global__ __launch_bounds__(256) void compact_kernel(const int* __restrict__ level,
                                                      int* __restrict__ rows_sorted,
                                                      int* __restrict__ offs) {
    __shared__ int cnt[NLEV + 1];
    __shared__ int off_s[NLEV + 1];
    int t = threadIdx.x;
    if (t <= NLEV) cnt[t] = 0;
    __syncthreads();
    for (int i = t; i < N; i += 256) atomicAdd(&cnt[level[i]], 1);
    __syncthreads();
    if (t == 0) {
        int run = 0;
        for (int l = 0; l < NLEV; ++l) { off_s[l] = run; run += cnt[l]; }
        off_s[NLEV] = run;  // == N
        for (int l = 0; l <= NLEV; ++l) offs[l] = off_s[l];
    }
    __syncthreads();
    if (t <= NLEV) cnt[t] = off_s[t];  // reuse as cursors
    __syncthreads();
    for (int i = t; i < N; i += 256) {
        int p = atomicAdd(&cnt[level[i]], 1);
        rows_sorted[p] = i;
    }
}

// ---------------- embedding GEMM: xhat = tfidf @ E_w ----------------
// grid (256 rowblocks, 2 ksplits), block 256. M_TILE=64. atomicAdd into zeroed xhat.
__global__ __launch_bounds__(256) void embed_kernel(const float* __restrict__ tfidf,
                                                    const float* __restrict__ Ew,
                                                    float* __restrict__ xhat) {
    __shared__ float a_lds[64][68];
    __shared__ float b_lds[64][68];
    int rb = blockIdx.x;
    int ks = blockIdx.y;
    int kstart = (ks == 0) ? 0 : 2496;
    int kend   = (ks == 0) ? 2496 : IN_DIM;
    int t = threadIdx.x;
    int rg = t >> 4;            // 0..15
    int c4 = (t & 15) * 4;      // 0..60
    int row0 = rb * 64;
    float acc[4][4] = {};
    for (int kt = kstart; kt < kend; kt += 64) {
        int kw = kend - kt; if (kw > 64) kw = 64;
        // stage A (tfidf rows), zero-padded tail
        #pragma unroll
        for (int i = 0; i < 4; i++) {
            int rl = i * 16 + rg;
            float4 v = make_float4(0.f, 0.f, 0.f, 0.f);
            const float* src = tfidf + (size_t)(row0 + rl) * IN_DIM + kt + c4;
            if (c4 + 3 < kw) {
                v = *(const float4*)src;
            } else {
                float tmp[4] = {0.f, 0.f, 0.f, 0.f};
                for (int q = 0; q < 4; q++) if (c4 + q < kw) tmp[q] = src[q];
                v = make_float4(tmp[0], tmp[1], tmp[2], tmp[3]);
            }
            *(float4*)&a_lds[rl][c4] = v;
        }
        // stage B (E_w rows), zero-padded tail
        #pragma unroll
        for (int i = 0; i < 4; i++) {
            int rl = i * 16 + rg;
            float4 v = make_float4(0.f, 0.f, 0.f, 0.f);
            if (rl < kw) v = *(const float4*)(Ew + (size_t)(kt + rl) * HID + c4);
            *(float4*)&b_lds[rl][c4] = v;
        }
        __syncthreads();
        #pragma unroll 8
        for (int k = 0; k < 64; k++) {
            float4 bv = *(const float4*)&b_lds[k][c4];
            #pragma unroll
            for (int i = 0; i < 4; i++) {
                float av = a_lds[4 * rg + i][k];
                acc[i][0] += av * bv.x; acc[i][1] += av * bv.y;
                acc[i][2] += av * bv.z; acc[i][3] += av * bv.w;
            }
        }
        __syncthreads();
    }
    #pragma unroll
    for (int i = 0; i < 4; i++) {
        int r = row0 + 4 * rg + i;
        #pragma unroll
        for (int m = 0; m < 4; m++)
            atomicAdd(&xhat[(size_t)r * HID + c4 + m], acc[i][m]);
    }
}

// ---------------- xr/xz/xh = xhat @ {Wr,Wz,Wh} ----------------
__global__ __launch_bounds__(256) void xproj_kernel(const float* __restrict__ xhat,
                                                    const float* __restrict__ Wr,
                                                    const float* __restrict__ Wz,
                                                    const float* __restrict__ Wh,
                                                    float* __restrict__ xr,
                                                    float* __restrict__ xz,
                                                    float* __restrict__ xh) {
    __shared__ float x_lds[64][68];
    __shared__ float w_lds[64][68];
    int t = threadIdx.x;
    int rg = t >> 4, c4 = (t & 15) * 4;
    int row0 = blockIdx.x * 64;
    #pragma unroll
    for (int i = 0; i < 4; i++) {
        int rl = i * 16 + rg;
        *(float4*)&x_lds[rl][c4] = *(const float4*)(xhat + (size_t)(row0 + rl) * HID + c4);
    }
    const float* Ws[3] = {Wr, Wz, Wh};
    float* outs[3] = {xr, xz, xh};
    for (int w = 0; w < 3; w++) {
        __syncthreads();
        #pragma unroll
        for (int i = 0; i < 4; i++) {
            int rl = i * 16 + rg;
            *(float4*)&w_lds[rl][c4] = *(const float4*)(Ws[w] + rl * HID + c4);
        }
        __syncthreads();
        float acc[4][4] = {};
        #pragma unroll 8
        for (int k = 0; k < 64; k++) {
            float4 bv = *(const float4*)&w_lds[k][c4];
            #pragma unroll
            for (int i = 0; i < 4; i++) {
                float av = x_lds[4 * rg + i][k];
                acc[i][0] += av * bv.x; acc[i][1] += av * bv.y;
                acc[i][2] += av * bv.z; acc[i][3] += av * bv.w;
            }
        }
        #pragma unroll
        for (int i = 0; i < 4; i++) {
            int r = row0 + 4 * rg + i;
            *(float4*)(outs[w] + (size_t)r * HID + c4) =
                make_float4(acc[i][0], acc[i][1], acc[i][2], acc[i][3]);
        }
    }
}

// ---------------- per-level masked GEMM: hs[rows] += adj[rows,:] @ h ----------------
// grid (256 rowblocks, SPLITK), block 256. 64 active rows per rowblock, K-chunk KCH.
__global__ __launch_bounds__(256) void hs_gemm(const float* __restrict__ adj,
                                               const float* __restrict__ h,
                                               float* __restrict__ hs,
                                               const int* __restrict__ rows_sorted,
                                               const int* __restrict__ offs, int lev) {
    __shared__ float a_lds[64][68];
    __shared__ float b_lds[64][68];
    __shared__ int ridx[64];
    int seg0 = offs[lev], seg1 = offs[lev + 1];
    int row0 = seg0 + blockIdx.x * 64;
    if (row0 >= seg1) return;
    int nval = seg1 - row0; if (nval > 64) nval = 64;
    int t = threadIdx.x;
    if (t < 64) {
        int p = row0 + t; if (p > seg1 - 1) p = seg1 - 1;
        ridx[t] = rows_sorted[p];
    }
    __syncthreads();
    int k0 = blockIdx.y * KCH;
    int rg = t >> 4, c4 = (t & 15) * 4;
    float acc[4][4] = {};
    for (int kt = 0; kt < KCH; kt += 64) {
        #pragma unroll
        for (int i = 0; i < 4; i++) {
            int rl = i * 16 + rg;
            float4 av = *(const float4*)(adj + (size_t)ridx[rl] * N + k0 + kt + c4);
            *(float4*)&a_lds[rl][c4] = av;
            float4 bv = *(const float4*)(h + (size_t)(k0 + kt + rl) * HID + c4);
            *(float4*)&b_lds[rl][c4] = bv;
        }
        __syncthreads();
        #pragma unroll 8
        for (int k = 0; k < 64; k++) {
            float4 bv = *(const float4*)&b_lds[k][c4];
            #pragma unroll
            for (int i = 0; i < 4; i++) {
                float av = a_lds[4 * rg + i][k];
                acc[i][0] += av * bv.x; acc[i][1] += av * bv.y;
                acc[i][2] += av * bv.z; acc[i][3] += av * bv.w;
            }
        }
        __syncthreads();
    }
    #pragma unroll
    for (int i = 0; i < 4; i++) {
        int lr = 4 * rg + i;
        if (lr < nval) {
            int r = ridx[lr];
            #pragma unroll
            for (int m = 0; m < 4; m++)
                atomicAdd(&hs[(size_t)r * HID + c4 + m], acc[i][m]);
        }
    }
}

// ---------------- per-level GRU gate update ----------------
// 16 active rows per block. Two passes (Uh needs full row of r*hs).
__global__ __launch_bounds__(256) void gate_kernel(const float* __restrict__ hs,
                                                   const float* __restrict__ xr,
                                                   const float* __restrict__ xz,
                                                   const float* __restrict__ xh,
                                                   const float* __restrict__ Ur,
                                                   const float* __restrict__ Uz,
                                                   const float* __restrict__ Uh,
                                                   float* __restrict__ h,
                                                   const int* __restrict__ rows_sorted,
                                                   const int* __restrict__ offs, int lev) {
    __shared__ float Ua[64][68];      // Ur, later Uh
    __shared__ float Ub[64][68];      // Uz
    __shared__ float hs_lds[16][68];
    __shared__ float rh_lds[16][68];
    __shared__ int ridx[16];
    int seg0 = offs[lev], seg1 = offs[lev + 1];
    int row0 = seg0 + blockIdx.x * 16;
    if (row0 >= seg1) return;
    int nval = seg1 - row0; if (nval > 16) nval = 16;
    int t = threadIdx.x;
    if (t < 16) { int p = row0 + t; if (p > seg1 - 1) p = seg1 - 1; ridx[t] = rows_sorted[p]; }
    int rg = t >> 4, c4 = (t & 15) * 4;
    #pragma unroll
    for (int i = 0; i < 4; i++) {
        int rl = i * 16 + rg;
        *(float4*)&Ua[rl][c4] = *(const float4*)(Ur + rl * HID + c4);
        *(float4*)&Ub[rl][c4] = *(const float4*)(Uz + rl * HID + c4);
    }
    __syncthreads();
    {   // stage hs rows (gathered)
        *(float4*)&hs_lds[rg][c4] = *(const float4*)(hs + (size_t)ridx[rg] * HID + c4);
    }
    __syncthreads();
    int row = rg;                 // 0..15
    int grow = ridx[row];
    float ur[4] = {}, uz[4] = {};
    #pragma unroll 8
    for (int k = 0; k < 64; k++) {
        float hv = hs_lds[row][k];
        float4 rv = *(const float4*)&Ua[k][c4];
        float4 zv = *(const float4*)&Ub[k][c4];
        ur[0] += hv * rv.x; ur[1] += hv * rv.y; ur[2] += hv * rv.z; ur[3] += hv * rv.w;
        uz[0] += hv * zv.x; uz[1] += hv * zv.y; uz[2] += hv * zv.z; uz[3] += hv * zv.w;
    }
    float zz[4], hsv[4];
    #pragma unroll
    for (int m = 0; m < 4; m++) {
        hsv[m] = hs_lds[row][c4 + m];
        float xrv = xr[(size_t)grow * HID + c4 + m];
        float xzv = xz[(size_t)grow * HID + c4 + m];
        float rr = 1.f / (1.f + expf(-(xrv + ur[m])));
        zz[m] = 1.f / (1.f + expf(-(xzv + uz[m])));
        rh_lds[row][c4 + m] = hsv[m] * rr;
    }
    __syncthreads();
    #pragma unroll
    for (int i = 0; i < 4; i++) {   // reload Ua with Uh
        int rl = i * 16 + rg;
        *(float4*)&Ua[rl][c4] = *(const float4*)(Uh + rl * HID + c4);
    }
    __syncthreads();
    float uh[4] = {};
    #pragma unroll 8
    for (int k = 0; k < 64; k++) {
        float rhv = rh_lds[row][k];
        float4 hv4 = *(const float4*)&Ua[k][c4];
        uh[0] += rhv * hv4.x; uh[1] += rhv * hv4.y; uh[2] += rhv * hv4.z; uh[3] += rhv * hv4.w;
    }
    if (row < nval) {
        #pragma unroll
        for (int m = 0; m < 4; m++) {
            float hh = tanhf(xh[(size_t)grow * HID + c4 + m] + uh[m]);
            float v = (1.f - zz[m]) * hsv[m] + zz[m] * hh;
            h[(size_t)grow * HID + c4 + m] = v;
        }
    }
}

// ---------------- root reduction + decoder ----------------
__global__ __launch_bounds__(256) void final_kernel(const float* __restrict__ h,
                                                    const float* __restrict__ dec_w,
                                                    const float* __restrict__ dec_b,
                                                    const int* __restrict__ rows_sorted,
                                                    const int* __restrict__ offs,
                                                    float* __restrict__ out) {
    __shared__ float part[4][64];
    __shared__ float rep[64];
    int t = threadIdx.x;
    int c = t & 63, g = t >> 6;
    int s0 = offs[0], s1 = offs[1];
    float sum = 0.f;
    for (int p = s0 + g; p < s1; p += 4) {
        int r = rows_sorted[p];
        sum += h[(size_t)r * HID + c];
    }
    part[g][c] = sum;
    __syncthreads();
    if (t < 64) rep[t] = part[0][t] + part[1][t] + part[2][t] + part[3][t];
    __syncthreads();
    if (t < 4) {
        float acc = dec_b[t];
        for (int k = 0; k < HID; k++) acc += rep[k] * dec_w[k * 4 + t];
        out[t] = acc;
    }
}

extern "C" void kernel_launch(void* const* d_in, const int* in_sizes, int n_in,
                              void* d_out, int out_size, void* d_ws, size_t ws_size,
                              hipStream_t stream) {
    const float* adj   = (const float*)d_in[0];
    const float* tfidf = (const float*)d_in[1];
    const int*   level = (const int*)d_in[2];
    const float* Ew    = (const float*)d_in[3];
    const float* Wr    = (const float*)d_in[4];
    const float* Wz    = (const float*)d_in[5];
    const float* Ur    = (const float*)d_in[6];
    const float* Uz    = (const float*)d_in[7];
    const float* Wh    = (const float*)d_in[8];
    const float* Uh    = (const float*)d_in[9];
    const float* decw  = (const float*)d_in[10];
    const float* decb  = (const float*)d_in[11];
    float* ws = (float*)d_ws;
    const size_t SL = (size_t)N * HID;
    float* xr   = ws;
    float* xz   = ws + SL;
    float* xh   = ws + 2 * SL;
    float* h    = ws + 3 * SL;
    float* hs   = ws + 4 * SL;
    float* xhat = ws + 5 * SL;
    int* rows_sorted = (int*)(ws + 6 * SL);
    int* offs = rows_sorted + N;
    float* out = (float*)d_out;

    // zero h, hs, xhat (contiguous)
    hipMemsetAsync(h, 0, 3 * SL * sizeof(float), stream);
    compact_kernel<<<1, 256, 0, stream>>>(level, rows_sorted, offs);
    embed_kernel<<<dim3(256, 2), 256, 0, stream>>>(tfidf, Ew, xhat);
    xproj_kernel<<<256, 256, 0, stream>>>(xhat, Wr, Wz, Wh, xr, xz, xh);
    for (int j = NLEV - 1; j >= 0; --j) {
        hs_gemm<<<dim3(256, SPLITK), 256, 0, stream>>>(adj, h, hs, rows_sorted, offs, j);
        gate_kernel<<<1024, 256, 0, stream>>>(hs, xr, xz, xh, Ur, Uz, Uh, h, rows_sorted, offs, j);
    }
    final_kernel<<<1, 256, 0, stream>>>(h, decw, decb, rows_sorted, offs, out);
}